// Round 3
// baseline (213.444 us; speedup 1.0000x reference)
//
#include <hip/hip_runtime.h>
#include <stddef.h>

// Problem constants (fixed by setup_inputs)
constexpr int B = 32;
constexpr int T = 2048;
constexpr int F = 512;   // K
constexpr int U = 128;   // N
constexpr float NEG_BIG = -1.0e9f;

typedef __attribute__((ext_vector_type(8))) short short8;   // MFMA A/B frag (8 bf16)
typedef __attribute__((ext_vector_type(4))) float f32x4;    // MFMA C/D frag

__device__ __forceinline__ unsigned short f2bf(float f) {
    unsigned int u = __float_as_uint(f);
    u += 0x7FFFu + ((u >> 16) & 1u);     // round-to-nearest-even
    return (unsigned short)(u >> 16);
}
__device__ __forceinline__ float bf2f(unsigned short h) {
    return __uint_as_float(((unsigned int)h) << 16);
}

// ---------------------------------------------------------------------------
// Prep: W1 [F,U] fp32 -> transposed split-bf16 W1T_hi/lo [U,F]. Tiny.
// ---------------------------------------------------------------------------
__global__ __launch_bounds__(256) void prep_w(
    const float* __restrict__ W1,
    unsigned short* __restrict__ WThi,
    unsigned short* __restrict__ WTlo)
{
    const int idx = blockIdx.x * 256 + threadIdx.x;   // 0..65535
    const int k = idx >> 7;          // F row
    const int u = idx & 127;         // U col
    const float w = W1[idx];
    const unsigned short hi = f2bf(w);
    const unsigned short lo = f2bf(w - bf2f(hi));
    WThi[(size_t)u * F + k] = hi;
    WTlo[(size_t)u * F + k] = lo;
}

// ---------------------------------------------------------------------------
// Pass 1: scores via split-bf16 MFMA, NO LDS / NO barriers.
// Waves split M: each wave owns 16 frames x all 128 u.
// A-frag: direct global load of x (lane l15 -> frame, g*8.. -> k), split to
// bf16 hi/lo in registers. B-frags: direct loads from L2-resident WT hi/lo.
// acc += x_hi*W_hi + x_hi*W_lo + x_lo*W_hi  (3 MFMAs, fp32 accumulate).
// Mask via __ballot of per-lane nonzero flags.
// ---------------------------------------------------------------------------
__global__ __launch_bounds__(256) void score_kernel(
    const float* __restrict__ x,            // [B*T, F]
    const unsigned short* __restrict__ WThi,// [U, F] bf16 bits
    const unsigned short* __restrict__ WTlo,// [U, F]
    const float* __restrict__ b1,           // [U]
    const float* __restrict__ W2,           // [U]
    const float* __restrict__ b2,           // [1]
    float* __restrict__ scores)             // [B*T]
{
    const int tid  = threadIdx.x;
    const int wid  = tid >> 6;
    const int lane = tid & 63;
    const int l15  = lane & 15;
    const int g    = lane >> 4;                 // k-group within wave
    const int m0   = blockIdx.x * 64 + wid * 16; // this wave's first frame

    const float* xrow = x + (size_t)(m0 + l15) * F + g * 8;
    const unsigned short* whr = WThi + (size_t)l15 * F + g * 8;
    const unsigned short* wlr = WTlo + (size_t)l15 * F + g * 8;

    f32x4 acc[8] = {};          // 8 n-frags (u = nf*16 + l15), fp32
    bool nzflag = false;

#pragma unroll 2
    for (int k0 = 0; k0 < F; k0 += 32) {
        const float4 a0 = *reinterpret_cast<const float4*>(xrow + k0);
        const float4 a1 = *reinterpret_cast<const float4*>(xrow + k0 + 4);
        const float av[8] = { a0.x, a0.y, a0.z, a0.w, a1.x, a1.y, a1.z, a1.w };
        short8 ah, al;
#pragma unroll
        for (int j = 0; j < 8; ++j) {
            const unsigned short hi = f2bf(av[j]);
            ah[j] = (short)hi;
            al[j] = (short)f2bf(av[j] - bf2f(hi));
            nzflag |= (av[j] != 0.0f);
        }
#pragma unroll
        for (int nf = 0; nf < 8; ++nf) {
            const short8 bh = *reinterpret_cast<const short8*>(
                whr + (size_t)(nf * 16) * F + k0);
            const short8 bl = *reinterpret_cast<const short8*>(
                wlr + (size_t)(nf * 16) * F + k0);
            acc[nf] = __builtin_amdgcn_mfma_f32_16x16x32_bf16(ah, bh, acc[nf], 0, 0, 0);
            acc[nf] = __builtin_amdgcn_mfma_f32_16x16x32_bf16(ah, bl, acc[nf], 0, 0, 0);
            acc[nf] = __builtin_amdgcn_mfma_f32_16x16x32_bf16(al, bh, acc[nf], 0, 0, 0);
        }
    }

    // frame f (= l15 of 4 lanes) nonzero iff any of ballot bits {f, f+16, f+32, f+48}
    const unsigned long long nzb = __ballot(nzflag);

    // epilogue constants for this lane's 8 u-columns
    float b1v[8], w2v[8];
#pragma unroll
    for (int nf = 0; nf < 8; ++nf) {
        const int u = nf * 16 + l15;
        b1v[nf] = b1[u];
        w2v[nf] = W2[u];
    }
    const float bias2 = b2[0];

    // C/D layout (HW-verified): col = lane&15, row = (lane>>4)*4 + reg.
#pragma unroll
    for (int r = 0; r < 4; ++r) {
        float s = 0.0f;
#pragma unroll
        for (int nf = 0; nf < 8; ++nf) {
            float h = acc[nf][r] + b1v[nf];
            h = h > 0.0f ? h : 0.0f;
            s += h * w2v[nf];
        }
        // sum across the 16 cols
        s += __shfl_xor(s, 1);
        s += __shfl_xor(s, 2);
        s += __shfl_xor(s, 4);
        s += __shfl_xor(s, 8);
        if (l15 == 0) {
            const int fr = g * 4 + r;            // frame within wave's 16
            const bool nz = (nzb & (0x0001000100010001ULL << fr)) != 0ULL;
            scores[m0 + fr] = nz ? (s + bias2) : NEG_BIG;
        }
    }
}

// ---------------------------------------------------------------------------
// Pass 2 (fused): per 256-frame chunk, compute top-k membership (stable
// rank-by-count, matching lax.top_k's lower-index-first ties), then stream
// the output slice: out[m,:] = sel[m] ? x[m,:] : 0.
// ---------------------------------------------------------------------------
__global__ __launch_bounds__(256) void topk_out_kernel(
    const float* __restrict__ scores,  // [B*T]
    const int* __restrict__ kp,        // [1]
    const float* __restrict__ x,       // [B*T, F]
    float* __restrict__ out)           // [B*T, F]
{
    __shared__ float srow[T];
    __shared__ int ssel[256];

    const int b     = blockIdx.x >> 3;   // 8 chunks of 256 frames per row
    const int chunk = blockIdx.x & 7;
    const float* row = scores + (size_t)b * T;

    for (int i = threadIdx.x; i < T / 4; i += 256)
        reinterpret_cast<float4*>(srow)[i] =
            reinterpret_cast<const float4*>(row)[i];
    __syncthreads();

    const int t   = chunk * 256 + threadIdx.x;
    const float s = srow[t];
    int cnt = 0;
    for (int i = 0; i < T / 4; ++i) {
        const float4 v = reinterpret_cast<const float4*>(srow)[i];
        const int base = i * 4;
        cnt += (v.x > s) || (v.x == s && (base + 0) < t);
        cnt += (v.y > s) || (v.y == s && (base + 1) < t);
        cnt += (v.z > s) || (v.z == s && (base + 2) < t);
        cnt += (v.w > s) || (v.w == s && (base + 3) < t);
    }
    ssel[threadIdx.x] = (cnt < kp[0]) ? 1 : 0;
    __syncthreads();

    // stream this chunk's 256 frames x 512 floats (= 32768 float4)
    const size_t base4 = ((size_t)b * T + (size_t)chunk * 256) * (F / 4);
    const float4* x4 = reinterpret_cast<const float4*>(x) + base4;
    float4*       o4 = reinterpret_cast<float4*>(out) + base4;
    const float4 z = make_float4(0.0f, 0.0f, 0.0f, 0.0f);

#pragma unroll 4
    for (int it = 0; it < 128; ++it) {
        const int q  = it * 256 + threadIdx.x;
        const int fr = q >> 7;              // frame within chunk (F/4 = 128)
        float4 v = z;
        if (ssel[fr]) v = x4[q];
        o4[q] = v;
    }
}

// ---------------------------------------------------------------------------
extern "C" void kernel_launch(void* const* d_in, const int* in_sizes, int n_in,
                              void* d_out, int out_size, void* d_ws, size_t ws_size,
                              hipStream_t stream)
{
    const float* x  = (const float*)d_in[0];
    const float* W1 = (const float*)d_in[1];
    const float* b1 = (const float*)d_in[2];
    const float* W2 = (const float*)d_in[3];
    const float* b2 = (const float*)d_in[4];
    const int*   kp = (const int*)d_in[5];

    char* ws = (char*)d_ws;
    unsigned short* WThi = (unsigned short*)ws;               // 131072 B
    unsigned short* WTlo = (unsigned short*)(ws + 131072);    // 131072 B
    float* scores        = (float*)(ws + 262144);             // 262144 B

    float* out = (float*)d_out;

    prep_w<<<256, 256, 0, stream>>>(W1, WThi, WTlo);
    score_kernel<<<(B * T) / 64, 256, 0, stream>>>(x, WThi, WTlo, b1, W2, b2, scores);
    topk_out_kernel<<<B * 8, 256, 0, stream>>>(scores, kp, x, out);
}

// Round 4
// 129.668 us; speedup vs baseline: 1.6461x; 1.6461x over previous
//
#include <hip/hip_runtime.h>
#include <stddef.h>

// Problem constants (fixed by setup_inputs)
constexpr int B = 32;
constexpr int T = 2048;
constexpr int F = 512;   // K
constexpr int U = 128;   // N
constexpr float NEG_BIG = -1.0e9f;

typedef __attribute__((ext_vector_type(8))) short short8;   // MFMA A/B frag (8 bf16)
typedef __attribute__((ext_vector_type(4))) float f32x4;    // MFMA C/D frag

__device__ __forceinline__ unsigned short f2bf(float f) {
    unsigned int u = __float_as_uint(f);
    u += 0x7FFFu + ((u >> 16) & 1u);     // round-to-nearest-even
    return (unsigned short)(u >> 16);
}
__device__ __forceinline__ float bf2f(unsigned short h) {
    return __uint_as_float(((unsigned int)h) << 16);
}

// ---------------------------------------------------------------------------
// Prep: W1 [F,U] fp32 -> transposed split-bf16 W1T_hi/lo [U,F]. Tiny.
// ---------------------------------------------------------------------------
__global__ __launch_bounds__(256) void prep_w(
    const float* __restrict__ W1,
    unsigned short* __restrict__ WThi,
    unsigned short* __restrict__ WTlo)
{
    const int idx = blockIdx.x * 256 + threadIdx.x;   // 0..65535
    const int k = idx >> 7;          // F row
    const int u = idx & 127;         // U col
    const float w = W1[idx];
    const unsigned short hi = f2bf(w);
    const unsigned short lo = f2bf(w - bf2f(hi));
    WThi[(size_t)u * F + k] = hi;
    WTlo[(size_t)u * F + k] = lo;
}

// ---------------------------------------------------------------------------
// Pass 1: scores via split-bf16 MFMA.
// 512 threads = 8 waves; each wave owns 16 frames x all 128 u.
// A (x): direct coalesced global load per k-step, split hi/lo in registers.
// B (W1T hi/lo): staged in LDS in 4 quarter-K phases (128 k each, 8 barriers
// total). Row stride LDK=132 elems = 66 words === 2 (mod 32): a 64-lane
// ds_read_b128 over 16 rows x 4 k-groups covers all 32 banks uniformly
// (8 words/bank = b128 minimum) -> conflict-free.
// acc += x_hi*W_hi + x_hi*W_lo + x_lo*W_hi  (split-bf16, fp32 accumulate).
// ---------------------------------------------------------------------------
constexpr int QK  = 128;   // k per stage phase
constexpr int LDK = 132;   // LDS row stride in bf16 elems

__global__ __launch_bounds__(512, 4) void score_kernel(
    const float* __restrict__ x,            // [B*T, F]
    const unsigned short* __restrict__ WThi,// [U, F] bf16 bits
    const unsigned short* __restrict__ WTlo,// [U, F]
    const float* __restrict__ b1,           // [U]
    const float* __restrict__ W2,           // [U]
    const float* __restrict__ b2,           // [1]
    float* __restrict__ scores)             // [B*T]
{
    __shared__ __align__(16) unsigned short wh[U * LDK];   // 33792 B
    __shared__ __align__(16) unsigned short wl[U * LDK];   // 33792 B

    const int tid  = threadIdx.x;
    const int wid  = tid >> 6;                  // 0..7
    const int lane = tid & 63;
    const int l15  = lane & 15;
    const int g    = lane >> 4;                 // k-group within wave
    const int m0   = blockIdx.x * 128 + wid * 16;

    const float* xrow = x + (size_t)(m0 + l15) * F + g * 8;

    // stage mapping: thread -> (row, 64B column group)
    const int sr = tid >> 2;                    // u-row 0..127
    const int sc = tid & 3;

    f32x4 acc[8] = {};          // 8 n-frags (u = nf*16 + l15), fp32
    bool nzflag = false;

    for (int q = 0; q < 4; ++q) {
        const int kbase = q * QK;

        // ---- stage W quarter: 128 u-rows x 128 k (hi & lo), 64 KB ----
#pragma unroll
        for (int it = 0; it < 4; ++it) {
            const int off = (sc + 4 * it) * 8;
            *reinterpret_cast<short8*>(&wh[sr * LDK + off]) =
                *reinterpret_cast<const short8*>(&WThi[(size_t)sr * F + kbase + off]);
            *reinterpret_cast<short8*>(&wl[sr * LDK + off]) =
                *reinterpret_cast<const short8*>(&WTlo[(size_t)sr * F + kbase + off]);
        }
        __syncthreads();

        // ---- compute 4 k32-steps from LDS ----
#pragma unroll
        for (int s = 0; s < 4; ++s) {
            const int k0 = kbase + s * 32;
            const float4 a0 = *reinterpret_cast<const float4*>(xrow + k0);
            const float4 a1 = *reinterpret_cast<const float4*>(xrow + k0 + 4);
            const float av[8] = { a0.x, a0.y, a0.z, a0.w, a1.x, a1.y, a1.z, a1.w };
            short8 ah, al;
#pragma unroll
            for (int j = 0; j < 8; ++j) {
                const unsigned short hi = f2bf(av[j]);
                ah[j] = (short)hi;
                al[j] = (short)f2bf(av[j] - bf2f(hi));
                nzflag |= (av[j] != 0.0f);
            }
            const int kloc = s * 32 + g * 8;
#pragma unroll
            for (int nf = 0; nf < 8; ++nf) {
                const int ub = (nf * 16 + l15) * LDK + kloc;
                const short8 bh = *reinterpret_cast<const short8*>(&wh[ub]);
                const short8 bl = *reinterpret_cast<const short8*>(&wl[ub]);
                acc[nf] = __builtin_amdgcn_mfma_f32_16x16x32_bf16(ah, bh, acc[nf], 0, 0, 0);
                acc[nf] = __builtin_amdgcn_mfma_f32_16x16x32_bf16(ah, bl, acc[nf], 0, 0, 0);
                acc[nf] = __builtin_amdgcn_mfma_f32_16x16x32_bf16(al, bh, acc[nf], 0, 0, 0);
            }
        }
        __syncthreads();
    }

    // frame f nonzero iff any ballot bit in {f, f+16, f+32, f+48}
    const unsigned long long nzb = __ballot(nzflag);

    // epilogue constants for this lane's 8 u-columns
    float b1v[8], w2v[8];
#pragma unroll
    for (int nf = 0; nf < 8; ++nf) {
        const int u = nf * 16 + l15;
        b1v[nf] = b1[u];
        w2v[nf] = W2[u];
    }
    const float bias2 = b2[0];

    // C/D layout (HW-verified): col = lane&15, row = (lane>>4)*4 + reg.
#pragma unroll
    for (int r = 0; r < 4; ++r) {
        float s = 0.0f;
#pragma unroll
        for (int nf = 0; nf < 8; ++nf) {
            float h = acc[nf][r] + b1v[nf];
            h = h > 0.0f ? h : 0.0f;
            s += h * w2v[nf];
        }
        s += __shfl_xor(s, 1);
        s += __shfl_xor(s, 2);
        s += __shfl_xor(s, 4);
        s += __shfl_xor(s, 8);
        if (l15 == 0) {
            const int fr = g * 4 + r;            // frame within wave's 16
            const bool nz = (nzb & (0x0001000100010001ULL << fr)) != 0ULL;
            scores[m0 + fr] = nz ? (s + bias2) : NEG_BIG;
        }
    }
}

// ---------------------------------------------------------------------------
// Pass 2 (fused): per 256-frame chunk, compute top-k membership (stable
// rank-by-count, matching lax.top_k's lower-index-first ties), then stream
// the output slice: out[m,:] = sel[m] ? x[m,:] : 0.
// ---------------------------------------------------------------------------
__global__ __launch_bounds__(256) void topk_out_kernel(
    const float* __restrict__ scores,  // [B*T]
    const int* __restrict__ kp,        // [1]
    const float* __restrict__ x,       // [B*T, F]
    float* __restrict__ out)           // [B*T, F]
{
    __shared__ float srow[T];
    __shared__ int ssel[256];

    const int b     = blockIdx.x >> 3;   // 8 chunks of 256 frames per row
    const int chunk = blockIdx.x & 7;
    const float* row = scores + (size_t)b * T;

    for (int i = threadIdx.x; i < T / 4; i += 256)
        reinterpret_cast<float4*>(srow)[i] =
            reinterpret_cast<const float4*>(row)[i];
    __syncthreads();

    const int t   = chunk * 256 + threadIdx.x;
    const float s = srow[t];
    int cnt = 0;
    for (int i = 0; i < T / 4; ++i) {
        const float4 v = reinterpret_cast<const float4*>(srow)[i];
        const int base = i * 4;
        cnt += (v.x > s) || (v.x == s && (base + 0) < t);
        cnt += (v.y > s) || (v.y == s && (base + 1) < t);
        cnt += (v.z > s) || (v.z == s && (base + 2) < t);
        cnt += (v.w > s) || (v.w == s && (base + 3) < t);
    }
    ssel[threadIdx.x] = (cnt < kp[0]) ? 1 : 0;
    __syncthreads();

    // stream this chunk's 256 frames x 512 floats (= 32768 float4)
    const size_t base4 = ((size_t)b * T + (size_t)chunk * 256) * (F / 4);
    const float4* x4 = reinterpret_cast<const float4*>(x) + base4;
    float4*       o4 = reinterpret_cast<float4*>(out) + base4;
    const float4 z = make_float4(0.0f, 0.0f, 0.0f, 0.0f);

#pragma unroll 4
    for (int it = 0; it < 128; ++it) {
        const int q  = it * 256 + threadIdx.x;
        const int fr = q >> 7;              // frame within chunk (F/4 = 128)
        float4 v = z;
        if (ssel[fr]) v = x4[q];
        o4[q] = v;
    }
}

// ---------------------------------------------------------------------------
extern "C" void kernel_launch(void* const* d_in, const int* in_sizes, int n_in,
                              void* d_out, int out_size, void* d_ws, size_t ws_size,
                              hipStream_t stream)
{
    const float* x  = (const float*)d_in[0];
    const float* W1 = (const float*)d_in[1];
    const float* b1 = (const float*)d_in[2];
    const float* W2 = (const float*)d_in[3];
    const float* b2 = (const float*)d_in[4];
    const int*   kp = (const int*)d_in[5];

    char* ws = (char*)d_ws;
    unsigned short* WThi = (unsigned short*)ws;               // 131072 B
    unsigned short* WTlo = (unsigned short*)(ws + 131072);    // 131072 B
    float* scores        = (float*)(ws + 262144);             // 262144 B

    float* out = (float*)d_out;

    prep_w<<<256, 256, 0, stream>>>(W1, WThi, WTlo);
    score_kernel<<<(B * T) / 128, 512, 0, stream>>>(x, WThi, WTlo, b1, W2, b2, scores);
    topk_out_kernel<<<B * 8, 256, 0, stream>>>(scores, kp, x, out);
}